// Round 1
// baseline (2205.414 us; speedup 1.0000x reference)
//
#include <hip/hip_runtime.h>
#include <math.h>

#define HEADS 4
#define CPH 256
#define DHID 1024
#define NEG_SLOPE 0.2f
#define FLT_BIG 3.402823466e38f
#define PCHUNK 128

typedef unsigned short u16;
typedef __bf16 bf16x8 __attribute__((ext_vector_type(8)));
typedef float f32x4 __attribute__((ext_vector_type(4)));
typedef float f32x16 __attribute__((ext_vector_type(16)));

__device__ __forceinline__ float lrelu(float x){ return x > 0.f ? x : NEG_SLOPE * x; }
__device__ __forceinline__ float eluf(float x){ return x > 0.f ? x : expf(x) - 1.f; }

__device__ __forceinline__ u16 f2bf(float f){
    unsigned u = __float_as_uint(f);
    u += 0x7fffu + ((u >> 16) & 1u);
    return (u16)(u >> 16);
}
__device__ __forceinline__ float bf2f(u16 h){ return __uint_as_float(((unsigned)h) << 16); }
__device__ __forceinline__ float4 bf4_to_f4(ushort4 u){
    return make_float4(bf2f(u.x), bf2f(u.y), bf2f(u.z), bf2f(u.w));
}

__device__ __forceinline__ void gload_lds16(const void* g, void* l){
    __builtin_amdgcn_global_load_lds((const __attribute__((address_space(1))) unsigned int*)g,
                                     (__attribute__((address_space(3))) unsigned int*)l, 16, 0, 0);
}

__device__ __forceinline__ void atomicMaxF(float* addr, float v){
    if (v >= 0.f) atomicMax((int*)addr, __float_as_int(v));
    else          atomicMin((unsigned int*)addr, __float_as_uint(v));
}

// ---------------- CSR build + pooling bounds ----------------
__global__ void k_init(int* cnt, int* fill, int* lo, int* hi, int N, int G){
    int i = blockIdx.x * blockDim.x + threadIdx.x;
    if (i < N){ cnt[i] = 0; fill[i] = 0; }
    if (i < G){ lo[i] = 0x7fffffff; hi[i] = 0; }
}

__global__ void k_count(const int* __restrict__ dst, int* __restrict__ cnt, int E){
    int e = blockIdx.x * blockDim.x + threadIdx.x;
    if (e < E) atomicAdd(&cnt[dst[e]], 1);
}

__global__ __launch_bounds__(1024) void k_scan(const int* __restrict__ cnt, int* __restrict__ rowptr,
                                               int N, int E){
    __shared__ int tot[1024];
    int tid = threadIdx.x;
    int items = (N + 1023) >> 10;
    int base = tid * items;
    int sum = 0;
    for (int i = 0; i < items; ++i){ int idx = base + i; if (idx < N) sum += cnt[idx]; }
    tot[tid] = sum;
    __syncthreads();
    for (int off = 1; off < 1024; off <<= 1){
        int t = (tid >= off) ? tot[tid - off] : 0;
        __syncthreads();
        tot[tid] += t;
        __syncthreads();
    }
    int run = tot[tid] - sum;
    for (int i = 0; i < items; ++i){
        int idx = base + i;
        if (idx < N){ rowptr[idx] = run; run += cnt[idx]; }
    }
    if (tid == 0) rowptr[N] = E;
}

__global__ void k_scatter(const int* __restrict__ src, const int* __restrict__ dst,
                          const int* __restrict__ rowptr, int* __restrict__ fill,
                          int* __restrict__ col, int E){
    int e = blockIdx.x * blockDim.x + threadIdx.x;
    if (e < E){
        int d = dst[e];
        int pos = rowptr[d] + atomicAdd(&fill[d], 1);
        col[pos] = src[e];
    }
}

__global__ void k_bounds(const int* __restrict__ batch, int* lo, int* hi, int N){
    int i = blockIdx.x * blockDim.x + threadIdx.x;
    if (i < N){
        int b = batch[i];
        atomicMin(&lo[b], i);
        atomicMax(&hi[b], i + 1);
    }
}

// ---------------- split kernels ----------------
__global__ void k_split(const float* __restrict__ X, u16* __restrict__ hi, u16* __restrict__ lo, long L4){
    long i = (long)blockIdx.x * blockDim.x + threadIdx.x;
    if (i < L4){
        float4 v = ((const float4*)X)[i];
        ushort4 h, l;
        h.x = f2bf(v.x); l.x = f2bf(v.x - bf2f(h.x));
        h.y = f2bf(v.y); l.y = f2bf(v.y - bf2f(h.y));
        h.z = f2bf(v.z); l.z = f2bf(v.z - bf2f(h.z));
        h.w = f2bf(v.w); l.w = f2bf(v.w - bf2f(h.w));
        ((ushort4*)hi)[i] = h;
        ((ushort4*)lo)[i] = l;
    }
}

__global__ void k_splitT(const float* __restrict__ W, u16* __restrict__ hiT, u16* __restrict__ loT,
                         int K, int Nn){
    int idx = blockIdx.x * blockDim.x + threadIdx.x;
    if (idx < K * Nn){
        int k = idx / Nn, n = idx - k * Nn;
        float v = W[idx];
        u16 h = f2bf(v);
        hiT[(size_t)n * K + k] = h;
        loT[(size_t)n * K + k] = f2bf(v - bf2f(h));
    }
}

// ---------------- split-bf16 MFMA GEMM (32x32x16), bf16 C store ----------------
// A (hi+lo) staged in LDS with 16B-chunk XOR swizzle (pre-swizzled global source,
// linear global_load_lds dest, swizzled ds_read -> conflict-free 8-phase b128).
// B (weights, L1/L2-resident panel) read directly from global into fragments.
__global__ __launch_bounds__(256) void k_gemm_mfma(
    const u16* __restrict__ Ahi, const u16* __restrict__ Alo,
    const u16* __restrict__ BThi, const u16* __restrict__ BTlo,
    u16* __restrict__ Cbf, int M, int K, int Nn, int Rchunk)
{
    __shared__ __align__(16) u16 As[2][128][32];   // [plane hi/lo][row][k], chunk-swizzled
    int tid = threadIdx.x;
    int w = tid >> 6, lane = tid & 63;

    int R = (M + 127) >> 7;
    int by = blockIdx.x * Rchunk + (blockIdx.y >> 3);   // gridDim.x==8 (XCD swizzle)
    int bx = blockIdx.y & 7;
    if (by >= R) return;
    int row0 = by * 128, col0 = bx * 128;

    // staging: thread tid -> LDS row srow, linear 16B chunk (tid&3); source chunk XOR-swizzled.
    int srow = tid >> 2;                 // 0..63 (and +64 for second half)
    int schunk = tid & 3;
    int ssw = (schunk ^ ((srow >> 1) & 3)) * 8;   // element offset in global k (pre-swizzle)
    // ((srow+64)>>1)&3 == ((srow>>1)&3): same swizzle class for both row halves.

    int wm = (w >> 1) * 64, wn = (w & 1) * 64;
    int l31 = lane & 31;
    int hi  = lane >> 5;

    f32x16 acc[2][2];
#pragma unroll
    for (int i = 0; i < 2; ++i)
#pragma unroll
        for (int j = 0; j < 2; ++j)
#pragma unroll
            for (int r = 0; r < 16; ++r) acc[i][j][r] = 0.f;

    int ra0 = row0 + srow;      if (ra0 >= M) ra0 = M - 1;
    int ra1 = row0 + srow + 64; if (ra1 >= M) ra1 = M - 1;

    // A fragment LDS addressing (rows wm + g*32 + l31, chunk = kk*2+hi, XOR-swizzled)
    int arow0 = wm + l31;
    int arow1 = wm + 32 + l31;
    int s0 = (arow0 >> 1) & 3;
    int s1 = (arow1 >> 1) & 3;
    int c000 = ((0 | hi) ^ s0) * 8;   // g=0, kk=0
    int c001 = ((2 | hi) ^ s0) * 8;   // g=0, kk=1
    int c010 = ((0 | hi) ^ s1) * 8;   // g=1, kk=0
    int c011 = ((2 | hi) ^ s1) * 8;   // g=1, kk=1

    // B fragment global base pointers (BT is N-major: BT[col][k])
    int cb0 = col0 + wn + l31;        // j=0 cols
    int cb1 = col0 + wn + 32 + l31;   // j=1 cols
    const u16* bh0p = BThi + (size_t)cb0 * K + hi * 8;
    const u16* bh1p = BThi + (size_t)cb1 * K + hi * 8;
    const u16* bl0p = BTlo + (size_t)cb0 * K + hi * 8;
    const u16* bl1p = BTlo + (size_t)cb1 * K + hi * 8;

    for (int k0 = 0; k0 < K; k0 += 32){
        size_t ga0 = (size_t)ra0 * K + k0 + ssw;
        size_t ga1 = (size_t)ra1 * K + k0 + ssw;
        gload_lds16(Ahi + ga0, &As[0][srow     ][schunk * 8]);
        gload_lds16(Ahi + ga1, &As[0][srow + 64][schunk * 8]);
        gload_lds16(Alo + ga0, &As[1][srow     ][schunk * 8]);
        gload_lds16(Alo + ga1, &As[1][srow + 64][schunk * 8]);

        // B fragments straight from global (L1-resident weight panel)
        bf16x8 bh[2][2], bl[2][2];
        bh[0][0] = *(const bf16x8*)(bh0p + k0);
        bh[0][1] = *(const bf16x8*)(bh0p + k0 + 16);
        bh[1][0] = *(const bf16x8*)(bh1p + k0);
        bh[1][1] = *(const bf16x8*)(bh1p + k0 + 16);
        bl[0][0] = *(const bf16x8*)(bl0p + k0);
        bl[0][1] = *(const bf16x8*)(bl0p + k0 + 16);
        bl[1][0] = *(const bf16x8*)(bl1p + k0);
        bl[1][1] = *(const bf16x8*)(bl1p + k0 + 16);
        __syncthreads();

        bf16x8 ah[2][2], al[2][2];
        ah[0][0] = *(const bf16x8*)&As[0][arow0][c000];
        ah[0][1] = *(const bf16x8*)&As[0][arow0][c001];
        ah[1][0] = *(const bf16x8*)&As[0][arow1][c010];
        ah[1][1] = *(const bf16x8*)&As[0][arow1][c011];
        al[0][0] = *(const bf16x8*)&As[1][arow0][c000];
        al[0][1] = *(const bf16x8*)&As[1][arow0][c001];
        al[1][0] = *(const bf16x8*)&As[1][arow1][c010];
        al[1][1] = *(const bf16x8*)&As[1][arow1][c011];

#pragma unroll
        for (int i = 0; i < 2; ++i)
#pragma unroll
            for (int j = 0; j < 2; ++j)
#pragma unroll
                for (int kk = 0; kk < 2; ++kk){
                    acc[i][j] = __builtin_amdgcn_mfma_f32_32x32x16_bf16(ah[i][kk], bh[j][kk], acc[i][j], 0, 0, 0);
                    acc[i][j] = __builtin_amdgcn_mfma_f32_32x32x16_bf16(ah[i][kk], bl[j][kk], acc[i][j], 0, 0, 0);
                    acc[i][j] = __builtin_amdgcn_mfma_f32_32x32x16_bf16(al[i][kk], bh[j][kk], acc[i][j], 0, 0, 0);
                }
        __syncthreads();
    }

    // C/D layout (32x32, HW-verified): col = lane&31, row = (reg&3) + 8*(reg>>2) + 4*(lane>>5)
#pragma unroll
    for (int i = 0; i < 2; ++i){
#pragma unroll
        for (int j = 0; j < 2; ++j){
            int colc = col0 + wn + j * 32 + l31;
#pragma unroll
            for (int r = 0; r < 16; ++r){
                int row = row0 + wm + i * 32 + (r & 3) + 8 * (r >> 2) + 4 * hi;
                if (row < M) Cbf[(size_t)row * Nn + colc] = f2bf(acc[i][j][r]);
            }
        }
    }
}

// ---------------- per-node attention score dots (bf16 h) ----------------
__global__ __launch_bounds__(256) void k_esd(const u16* __restrict__ h, const float* __restrict__ asrc,
                                             const float* __restrict__ adst,
                                             float* __restrict__ es, float* __restrict__ ed){
    int n = blockIdx.x;
    int tid = threadIdx.x;
    int w = tid >> 6, lane = tid & 63;
    float4 hv = bf4_to_f4(*(const ushort4*)(h + (size_t)n * DHID + w * CPH + lane * 4));
    float4 av = *(const float4*)(asrc + w * CPH + lane * 4);
    float4 dv = *(const float4*)(adst + w * CPH + lane * 4);
    float s = hv.x * av.x + hv.y * av.y + hv.z * av.z + hv.w * av.w;
    float d = hv.x * dv.x + hv.y * dv.y + hv.z * dv.z + hv.w * dv.w;
    for (int off = 32; off > 0; off >>= 1){
        s += __shfl_down(s, off);
        d += __shfl_down(d, off);
    }
    if (lane == 0){ es[n * HEADS + w] = s; ed[n * HEADS + w] = d; }
}

// ---------------- wave-per-node segment softmax + aggregation + bias + elu + split write ----------------
// block = 256 threads = 4 waves, wave i handles node blockIdx.x*4+i.
// Lane covers channels {h*256 + lane*4 ..+3} for all 4 heads -> full 2KB contiguous row per edge.
__global__ __launch_bounds__(256) void k_agg(const u16* __restrict__ hsrc, const float* __restrict__ es,
                                             const float* __restrict__ ed, const int* __restrict__ rowptr,
                                             const int* __restrict__ col, const float* __restrict__ bias,
                                             u16* __restrict__ outhi, u16* __restrict__ outlo,
                                             int writeLo, int N){
    int n = blockIdx.x * 4 + (threadIdx.x >> 6);
    if (n >= N) return;
    int lane = threadIdx.x & 63;
    int rp0 = rowptr[n];
    int deg = rowptr[n + 1] - rp0;
    int total = deg + 1;                         // + implicit self-loop
    float4 edv = *(const float4*)(ed + (size_t)n * HEADS);

    // pass 1: per-head max over incoming edges
    float4 mx = make_float4(-FLT_BIG, -FLT_BIG, -FLT_BIG, -FLT_BIG);
    for (int i = lane; i < total; i += 64){
        int s = (i < deg) ? col[rp0 + i] : n;
        float4 ev = *(const float4*)(es + (size_t)s * HEADS);
        mx.x = fmaxf(mx.x, lrelu(ev.x + edv.x));
        mx.y = fmaxf(mx.y, lrelu(ev.y + edv.y));
        mx.z = fmaxf(mx.z, lrelu(ev.z + edv.z));
        mx.w = fmaxf(mx.w, lrelu(ev.w + edv.w));
    }
#pragma unroll
    for (int off = 1; off < 64; off <<= 1){
        mx.x = fmaxf(mx.x, __shfl_xor(mx.x, off));
        mx.y = fmaxf(mx.y, __shfl_xor(mx.y, off));
        mx.z = fmaxf(mx.z, __shfl_xor(mx.z, off));
        mx.w = fmaxf(mx.w, __shfl_xor(mx.w, off));
    }

    // pass 2: per-head sum of exp(e - m)  (es now L1-hot)
    float4 sm = make_float4(0.f, 0.f, 0.f, 0.f);
    for (int i = lane; i < total; i += 64){
        int s = (i < deg) ? col[rp0 + i] : n;
        float4 ev = *(const float4*)(es + (size_t)s * HEADS);
        sm.x += expf(lrelu(ev.x + edv.x) - mx.x);
        sm.y += expf(lrelu(ev.y + edv.y) - mx.y);
        sm.z += expf(lrelu(ev.z + edv.z) - mx.z);
        sm.w += expf(lrelu(ev.w + edv.w) - mx.w);
    }
#pragma unroll
    for (int off = 1; off < 64; off <<= 1){
        sm.x += __shfl_xor(sm.x, off);
        sm.y += __shfl_xor(sm.y, off);
        sm.z += __shfl_xor(sm.z, off);
        sm.w += __shfl_xor(sm.w, off);
    }
    float4 inv = make_float4(1.f / (sm.x + 1e-16f), 1.f / (sm.y + 1e-16f),
                             1.f / (sm.z + 1e-16f), 1.f / (sm.w + 1e-16f));

    // pass 3: weighted aggregation — wave reads the full 2KB row per edge (4 x 512B)
    float4 a0 = make_float4(0.f,0.f,0.f,0.f), a1 = a0, a2 = a0, a3 = a0;
    int c4 = lane * 4;
    for (int i = 0; i < total; ++i){
        int s = (i < deg) ? col[rp0 + i] : n;           // wave-uniform
        float4 ev = *(const float4*)(es + (size_t)s * HEADS);   // L1-hot broadcast
        const u16* rowp = hsrc + (size_t)s * DHID;
        ushort4 r0 = *(const ushort4*)(rowp + 0 * CPH + c4);
        ushort4 r1 = *(const ushort4*)(rowp + 1 * CPH + c4);
        ushort4 r2 = *(const ushort4*)(rowp + 2 * CPH + c4);
        ushort4 r3 = *(const ushort4*)(rowp + 3 * CPH + c4);
        float alx = expf(lrelu(ev.x + edv.x) - mx.x) * inv.x;
        float aly = expf(lrelu(ev.y + edv.y) - mx.y) * inv.y;
        float alz = expf(lrelu(ev.z + edv.z) - mx.z) * inv.z;
        float alw = expf(lrelu(ev.w + edv.w) - mx.w) * inv.w;
        float4 f0 = bf4_to_f4(r0), f1 = bf4_to_f4(r1), f2 = bf4_to_f4(r2), f3 = bf4_to_f4(r3);
        a0.x = fmaf(alx, f0.x, a0.x); a0.y = fmaf(alx, f0.y, a0.y);
        a0.z = fmaf(alx, f0.z, a0.z); a0.w = fmaf(alx, f0.w, a0.w);
        a1.x = fmaf(aly, f1.x, a1.x); a1.y = fmaf(aly, f1.y, a1.y);
        a1.z = fmaf(aly, f1.z, a1.z); a1.w = fmaf(aly, f1.w, a1.w);
        a2.x = fmaf(alz, f2.x, a2.x); a2.y = fmaf(alz, f2.y, a2.y);
        a2.z = fmaf(alz, f2.z, a2.z); a2.w = fmaf(alz, f2.w, a2.w);
        a3.x = fmaf(alw, f3.x, a3.x); a3.y = fmaf(alw, f3.y, a3.y);
        a3.z = fmaf(alw, f3.z, a3.z); a3.w = fmaf(alw, f3.w, a3.w);
    }

    // epilogue: +bias, elu, bf16 hi(/lo) store per head
#pragma unroll
    for (int h = 0; h < 4; ++h){
        float4 a = (h == 0) ? a0 : (h == 1) ? a1 : (h == 2) ? a2 : a3;
        int cidx = h * CPH + c4;
        float4 bv = *(const float4*)(bias + cidx);
        float ox = eluf(a.x + bv.x);
        float oy = eluf(a.y + bv.y);
        float oz = eluf(a.z + bv.z);
        float ow = eluf(a.w + bv.w);
        ushort4 h4;
        h4.x = f2bf(ox); h4.y = f2bf(oy); h4.z = f2bf(oz); h4.w = f2bf(ow);
        *(ushort4*)(outhi + (size_t)n * DHID + cidx) = h4;
        if (writeLo){
            ushort4 l4;
            l4.x = f2bf(ox - bf2f(h4.x));
            l4.y = f2bf(oy - bf2f(h4.y));
            l4.z = f2bf(oz - bf2f(h4.z));
            l4.w = f2bf(ow - bf2f(h4.w));
            *(ushort4*)(outlo + (size_t)n * DHID + cidx) = l4;
        }
    }
}

// ---------------- two-stage per-graph mean/max pooling (bf16 input) ----------------
__global__ __launch_bounds__(256) void k_pool_init(float* __restrict__ gsum, float* __restrict__ gmax, int L){
    int i = blockIdx.x * blockDim.x + threadIdx.x;
    if (i < L){ gsum[i] = 0.f; gmax[i] = -FLT_BIG; }
}

__global__ __launch_bounds__(256) void k_pool_partial(const u16* __restrict__ hf,
                                                      const int* __restrict__ batch,
                                                      float* __restrict__ gsum, float* __restrict__ gmax,
                                                      int N){
    int c = blockIdx.y * 256 + threadIdx.x;
    int i0 = blockIdx.x * PCHUNK;
    int i1 = i0 + PCHUNK; if (i1 > N) i1 = N;
    int curg = batch[i0];
    float s = 0.f, m = -FLT_BIG;
    for (int i = i0; i < i1; ++i){
        int g = batch[i];
        if (g != curg){
            atomicAdd(&gsum[(size_t)curg * DHID + c], s);
            atomicMaxF(&gmax[(size_t)curg * DHID + c], m);
            s = 0.f; m = -FLT_BIG; curg = g;
        }
        float v = bf2f(hf[(size_t)i * DHID + c]);
        s += v;
        m = fmaxf(m, v);
    }
    atomicAdd(&gsum[(size_t)curg * DHID + c], s);
    atomicMaxF(&gmax[(size_t)curg * DHID + c], m);
}

__global__ __launch_bounds__(256) void k_pool_final(const float* __restrict__ gsum,
                                                    const float* __restrict__ gmax,
                                                    const int* __restrict__ lo, const int* __restrict__ hi,
                                                    float* __restrict__ gfeat){
    int g = blockIdx.x;
    int c = threadIdx.x * 4;
    int l = lo[g], h2 = hi[g];
    int cnt = (h2 > l) ? (h2 - l) : 0;
    float invc = 1.f / (float)((cnt > 1) ? cnt : 1);
    float4 s = *(const float4*)(gsum + (size_t)g * DHID + c);
    float4 m = *(const float4*)(gmax + (size_t)g * DHID + c);
    float4 mean = make_float4(s.x * invc, s.y * invc, s.z * invc, s.w * invc);
    if (cnt == 0) m = make_float4(0.f, 0.f, 0.f, 0.f);
    *(float4*)(gfeat + (size_t)g * 2048 + c)        = mean;
    *(float4*)(gfeat + (size_t)g * 2048 + 1024 + c) = m;
}

// ---------------- small FC ----------------
__global__ __launch_bounds__(256) void k_fc(const float* __restrict__ X, const float* __restrict__ W,
                                            const float* __restrict__ b, float* __restrict__ Y,
                                            int K, int Nc, int relu){
    __shared__ float xr[2048];
    int r = blockIdx.y;
    int tid = threadIdx.x;
    for (int i = tid; i < K; i += 256) xr[i] = X[(size_t)r * K + i];
    __syncthreads();
    int c = blockIdx.x * 256 + tid;
    if (c >= Nc) return;
    float acc = b[c];
    for (int k = 0; k < K; ++k) acc += xr[k] * W[(size_t)k * Nc + c];
    if (relu) acc = fmaxf(acc, 0.f);
    Y[(size_t)r * Nc + c] = acc;
}

// ---------------- launch ----------------
extern "C" void kernel_launch(void* const* d_in, const int* in_sizes, int n_in,
                              void* d_out, int out_size, void* d_ws, size_t ws_size,
                              hipStream_t stream) {
    const float* x      = (const float*)d_in[0];
    const int*   ei     = (const int*)  d_in[1];
    const int*   batch  = (const int*)  d_in[2];
    const float* W1     = (const float*)d_in[3];
    const float* asrc1  = (const float*)d_in[4];
    const float* adst1  = (const float*)d_in[5];
    const float* b1     = (const float*)d_in[6];
    const float* W2     = (const float*)d_in[7];
    const float* asrc2  = (const float*)d_in[8];
    const float* adst2  = (const float*)d_in[9];
    const float* b2     = (const float*)d_in[10];
    const float* Wc1    = (const float*)d_in[11];
    const float* bc1    = (const float*)d_in[12];
    const float* Wc2    = (const float*)d_in[13];
    const float* bc2    = (const float*)d_in[14];
    const float* Wc3    = (const float*)d_in[15];
    const float* bc3    = (const float*)d_in[16];

    const int N = in_sizes[2];
    const int E = in_sizes[1] / 2;
    const int G = out_size / 5;
    const int DIN = in_sizes[0] / N;

    const int* srcI = ei;
    const int* dstI = ei + E;

    char* p = (char*)d_ws;
    auto alloc = [&](size_t bytes) -> void* {
        void* q = (void*)p;
        p += (bytes + 255) & ~(size_t)255;
        return q;
    };
    u16*   R1     = (u16*)alloc((size_t)N * DHID * 2 * 2);   // activations hi+lo
    u16*   R2     = (u16*)alloc((size_t)N * DHID * 2);       // bf16 h plane
    float* es     = (float*)alloc((size_t)N * HEADS * 4);
    float* ed     = (float*)alloc((size_t)N * HEADS * 4);
    float* gfeat  = (float*)alloc((size_t)G * 2048 * 4);
    float* gsum   = (float*)alloc((size_t)G * DHID * 4);
    float* gmax   = (float*)alloc((size_t)G * DHID * 4);
    float* z1     = (float*)alloc((size_t)G * 512 * 4);
    float* z2     = (float*)alloc((size_t)G * 256 * 4);
    int*   cnt    = (int*)  alloc((size_t)N * 4);
    int*   fill   = (int*)  alloc((size_t)N * 4);
    int*   rowptr = (int*)  alloc((size_t)(N + 1) * 4);
    int*   col    = (int*)  alloc((size_t)E * 4);
    int*   lo     = (int*)  alloc((size_t)G * 4);
    int*   hi     = (int*)  alloc((size_t)G * 4);
    u16*   w1th   = (u16*)  alloc((size_t)DIN * DHID * 2);
    u16*   w1tl   = (u16*)  alloc((size_t)DIN * DHID * 2);
    u16*   w2th   = (u16*)  alloc((size_t)DHID * DHID * 2);
    u16*   w2tl   = (u16*)  alloc((size_t)DHID * DHID * 2);
    float* logits = (float*)d_out;

    int nb = (N + 255) / 256;
    int ebp = (E + 255) / 256;
    int aggb = (N + 3) / 4;

    // CSR + pooling bounds
    k_init   <<<nb,  256, 0, stream>>>(cnt, fill, lo, hi, N, G);
    k_count  <<<ebp, 256, 0, stream>>>(dstI, cnt, E);
    k_scan   <<<1,  1024, 0, stream>>>(cnt, rowptr, N, E);
    k_scatter<<<ebp, 256, 0, stream>>>(srcI, dstI, rowptr, fill, col, E);
    k_bounds <<<nb,  256, 0, stream>>>(batch, lo, hi, N);

    // weight splits (with transpose)
    k_splitT<<<(DIN * DHID + 255) / 256, 256, 0, stream>>>(W1, w1th, w1tl, DIN, DHID);
    k_splitT<<<(DHID * DHID + 255) / 256, 256, 0, stream>>>(W2, w2th, w2tl, DHID, DHID);

    int R = (N + 127) / 128;
    int Rchunk = (R + 7) / 8;
    dim3 gemmGrd(8, 8 * Rchunk);   // XCD swizzle: x = row-chunk, y = (local row, col-block)

    // ---- GAT layer 1 ----
    u16* a1h = R1;
    u16* a1l = R1 + (size_t)N * DIN;
    long L41 = (long)N * DIN / 4;
    k_split<<<(unsigned)((L41 + 255) / 256), 256, 0, stream>>>(x, a1h, a1l, L41);
    u16* h1 = R2;
    k_gemm_mfma<<<gemmGrd, 256, 0, stream>>>(a1h, a1l, w1th, w1tl, h1, N, DIN, DHID, Rchunk);
    k_esd<<<N, 256, 0, stream>>>(h1, asrc1, adst1, es, ed);
    u16* o1h = R1;
    u16* o1l = R1 + (size_t)N * DHID;
    k_agg<<<aggb, 256, 0, stream>>>(h1, es, ed, rowptr, col, b1, o1h, o1l, 1, N);

    // ---- GAT layer 2 ----
    u16* h2 = R2;
    k_gemm_mfma<<<gemmGrd, 256, 0, stream>>>(o1h, o1l, w2th, w2tl, h2, N, DHID, DHID, Rchunk);
    k_esd<<<N, 256, 0, stream>>>(h2, asrc2, adst2, es, ed);
    u16* o2h = R1;
    k_agg<<<aggb, 256, 0, stream>>>(h2, es, ed, rowptr, col, b2, o2h, (u16*)0, 0, N);

    // ---- pooling + classifier ----
    k_pool_init<<<(G * DHID + 255) / 256, 256, 0, stream>>>(gsum, gmax, G * DHID);
    dim3 poolGrd((N + PCHUNK - 1) / PCHUNK, DHID / 256);
    k_pool_partial<<<poolGrd, 256, 0, stream>>>(o2h, batch, gsum, gmax, N);
    k_pool_final<<<G, 256, 0, stream>>>(gsum, gmax, lo, hi, gfeat);

    k_fc<<<dim3(2, G), 256, 0, stream>>>(gfeat, Wc1, bc1, z1, 2048, 512, 1);
    k_fc<<<dim3(1, G), 256, 0, stream>>>(z1,    Wc2, bc2, z2, 512,  256, 1);
    k_fc<<<dim3(1, G), 256, 0, stream>>>(z2,    Wc3, bc3, logits, 256, 5, 0);
}

// Round 2
// 1857.443 us; speedup vs baseline: 1.1873x; 1.1873x over previous
//
#include <hip/hip_runtime.h>
#include <math.h>

#define HEADS 4
#define CPH 256
#define DHID 1024
#define NEG_SLOPE 0.2f
#define FLT_BIG 3.402823466e38f
#define PCHUNK 128

typedef unsigned short u16;
typedef __bf16 bf16x8 __attribute__((ext_vector_type(8)));
typedef float f32x4 __attribute__((ext_vector_type(4)));
typedef float f32x16 __attribute__((ext_vector_type(16)));

__device__ __forceinline__ float lrelu(float x){ return x > 0.f ? x : NEG_SLOPE * x; }
__device__ __forceinline__ float eluf(float x){ return x > 0.f ? x : expf(x) - 1.f; }

__device__ __forceinline__ u16 f2bf(float f){
    unsigned u = __float_as_uint(f);
    u += 0x7fffu + ((u >> 16) & 1u);
    return (u16)(u >> 16);
}
__device__ __forceinline__ float bf2f(u16 h){ return __uint_as_float(((unsigned)h) << 16); }
__device__ __forceinline__ float4 bf4_to_f4(ushort4 u){
    return make_float4(bf2f(u.x), bf2f(u.y), bf2f(u.z), bf2f(u.w));
}

__device__ __forceinline__ void gload_lds16(const void* g, void* l){
    __builtin_amdgcn_global_load_lds((const __attribute__((address_space(1))) unsigned int*)g,
                                     (__attribute__((address_space(3))) unsigned int*)l, 16, 0, 0);
}

__device__ __forceinline__ void atomicMaxF(float* addr, float v){
    if (v >= 0.f) atomicMax((int*)addr, __float_as_int(v));
    else          atomicMin((unsigned int*)addr, __float_as_uint(v));
}

// ---------------- CSR build + pooling bounds ----------------
__global__ void k_init(int* cnt, int* fill, int* lo, int* hi, int N, int G){
    int i = blockIdx.x * blockDim.x + threadIdx.x;
    if (i < N){ cnt[i] = 0; fill[i] = 0; }
    if (i < G){ lo[i] = 0x7fffffff; hi[i] = 0; }
}

__global__ void k_count(const int* __restrict__ dst, int* __restrict__ cnt, int E){
    int e = blockIdx.x * blockDim.x + threadIdx.x;
    if (e < E) atomicAdd(&cnt[dst[e]], 1);
}

__global__ __launch_bounds__(1024) void k_scan(const int* __restrict__ cnt, int* __restrict__ rowptr,
                                               int N, int E){
    __shared__ int tot[1024];
    int tid = threadIdx.x;
    int items = (N + 1023) >> 10;
    int base = tid * items;
    int sum = 0;
    for (int i = 0; i < items; ++i){ int idx = base + i; if (idx < N) sum += cnt[idx]; }
    tot[tid] = sum;
    __syncthreads();
    for (int off = 1; off < 1024; off <<= 1){
        int t = (tid >= off) ? tot[tid - off] : 0;
        __syncthreads();
        tot[tid] += t;
        __syncthreads();
    }
    int run = tot[tid] - sum;
    for (int i = 0; i < items; ++i){
        int idx = base + i;
        if (idx < N){ rowptr[idx] = run; run += cnt[idx]; }
    }
    if (tid == 0) rowptr[N] = E;
}

__global__ void k_scatter(const int* __restrict__ src, const int* __restrict__ dst,
                          const int* __restrict__ rowptr, int* __restrict__ fill,
                          int* __restrict__ col, int E){
    int e = blockIdx.x * blockDim.x + threadIdx.x;
    if (e < E){
        int d = dst[e];
        int pos = rowptr[d] + atomicAdd(&fill[d], 1);
        col[pos] = src[e];
    }
}

__global__ void k_bounds(const int* __restrict__ batch, int* lo, int* hi, int N){
    int i = blockIdx.x * blockDim.x + threadIdx.x;
    if (i < N){
        int b = batch[i];
        atomicMin(&lo[b], i);
        atomicMax(&hi[b], i + 1);
    }
}

// ---------------- split kernels ----------------
__global__ void k_split(const float* __restrict__ X, u16* __restrict__ hi, u16* __restrict__ lo, long L4){
    long i = (long)blockIdx.x * blockDim.x + threadIdx.x;
    if (i < L4){
        float4 v = ((const float4*)X)[i];
        ushort4 h, l;
        h.x = f2bf(v.x); l.x = f2bf(v.x - bf2f(h.x));
        h.y = f2bf(v.y); l.y = f2bf(v.y - bf2f(h.y));
        h.z = f2bf(v.z); l.z = f2bf(v.z - bf2f(h.z));
        h.w = f2bf(v.w); l.w = f2bf(v.w - bf2f(h.w));
        ((ushort4*)hi)[i] = h;
        ((ushort4*)lo)[i] = l;
    }
}

// LDS-tiled transpose split: W (K x Nn, row-major) -> hiT/loT (Nn x K, row-major).
// Both global read and both global writes are coalesced (32x32 f32 tile, padded LDS).
__global__ __launch_bounds__(256) void k_splitT(const float* __restrict__ W, u16* __restrict__ hiT,
                                                u16* __restrict__ loT, int K, int Nn){
    __shared__ float t[32][33];
    int n0 = blockIdx.x * 32;
    int k0 = blockIdx.y * 32;
    int tx = threadIdx.x & 31, ty = threadIdx.x >> 5;   // 8 rows per pass
    for (int r = ty; r < 32; r += 8){
        int k = k0 + r, n = n0 + tx;
        t[r][tx] = (k < K && n < Nn) ? W[(size_t)k * Nn + n] : 0.f;
    }
    __syncthreads();
    for (int r = ty; r < 32; r += 8){
        int n = n0 + r, k = k0 + tx;
        if (n < Nn && k < K){
            float v = t[tx][r];
            u16 h = f2bf(v);
            hiT[(size_t)n * K + k] = h;
            loT[(size_t)n * K + k] = f2bf(v - bf2f(h));
        }
    }
}

// ---------------- split-bf16 MFMA GEMM (32x32x16), both operands LDS-staged ----------------
// A and B (hi+lo) staged via global_load_lds with 16B-chunk XOR swizzle
// (pre-swizzled global source, linear LDS dest, swizzled ds_read).
__global__ __launch_bounds__(256) void k_gemm_mfma(
    const u16* __restrict__ Ahi, const u16* __restrict__ Alo,
    const u16* __restrict__ BThi, const u16* __restrict__ BTlo,
    u16* __restrict__ Cbf, int M, int K, int Nn, int Rchunk)
{
    __shared__ __align__(16) u16 As[2][128][32];   // [plane hi/lo][row][k], chunk-swizzled
    __shared__ __align__(16) u16 Bs[2][128][32];
    int tid = threadIdx.x;
    int w = tid >> 6, lane = tid & 63;

    int R = (M + 127) >> 7;
    int by = blockIdx.x * Rchunk + (blockIdx.y >> 3);   // gridDim.x==8 (XCD swizzle)
    int bx = blockIdx.y & 7;
    if (by >= R) return;
    int row0 = by * 128, col0 = bx * 128;

    // staging: thread tid -> LDS row srow, linear 16B chunk (tid&3); source chunk XOR-swizzled.
    int srow = tid >> 2;                 // 0..63 (and +64 for second half)
    int schunk = tid & 3;
    int ssw = (schunk ^ ((srow >> 1) & 3)) * 8;   // element offset in global k (pre-swizzle)
    // ((srow+64)>>1)&3 == ((srow>>1)&3): same swizzle class for both row halves.

    int wm = (w >> 1) * 64, wn = (w & 1) * 64;
    int l31 = lane & 31;
    int hi  = lane >> 5;

    f32x16 acc[2][2];
#pragma unroll
    for (int i = 0; i < 2; ++i)
#pragma unroll
        for (int j = 0; j < 2; ++j)
#pragma unroll
            for (int r = 0; r < 16; ++r) acc[i][j][r] = 0.f;

    int ra0 = row0 + srow;      if (ra0 >= M) ra0 = M - 1;
    int ra1 = row0 + srow + 64; if (ra1 >= M) ra1 = M - 1;
    int rb0 = col0 + srow;
    int rb1 = col0 + srow + 64;

    // fragment LDS chunk offsets (rows wm/wn + g*32 + l31, chunk = kk*2+hi, XOR-swizzled)
    int arow0 = wm + l31;
    int arow1 = wm + 32 + l31;
    int sA0 = (arow0 >> 1) & 3;
    int sA1 = (arow1 >> 1) & 3;
    int a00 = ((0 | hi) ^ sA0) * 8;   // g=0, kk=0
    int a01 = ((2 | hi) ^ sA0) * 8;   // g=0, kk=1
    int a10 = ((0 | hi) ^ sA1) * 8;   // g=1, kk=0
    int a11 = ((2 | hi) ^ sA1) * 8;   // g=1, kk=1
    int brow0 = wn + l31;
    int brow1 = wn + 32 + l31;
    int sB0 = (brow0 >> 1) & 3;
    int sB1 = (brow1 >> 1) & 3;
    int b00 = ((0 | hi) ^ sB0) * 8;
    int b01 = ((2 | hi) ^ sB0) * 8;
    int b10 = ((0 | hi) ^ sB1) * 8;
    int b11 = ((2 | hi) ^ sB1) * 8;

    for (int k0 = 0; k0 < K; k0 += 32){
        size_t ga0 = (size_t)ra0 * K + k0 + ssw;
        size_t ga1 = (size_t)ra1 * K + k0 + ssw;
        size_t gb0 = (size_t)rb0 * K + k0 + ssw;
        size_t gb1 = (size_t)rb1 * K + k0 + ssw;
        gload_lds16(Ahi  + ga0, &As[0][srow     ][schunk * 8]);
        gload_lds16(Ahi  + ga1, &As[0][srow + 64][schunk * 8]);
        gload_lds16(Alo  + ga0, &As[1][srow     ][schunk * 8]);
        gload_lds16(Alo  + ga1, &As[1][srow + 64][schunk * 8]);
        gload_lds16(BThi + gb0, &Bs[0][srow     ][schunk * 8]);
        gload_lds16(BThi + gb1, &Bs[0][srow + 64][schunk * 8]);
        gload_lds16(BTlo + gb0, &Bs[1][srow     ][schunk * 8]);
        gload_lds16(BTlo + gb1, &Bs[1][srow + 64][schunk * 8]);
        __syncthreads();

        bf16x8 ah[2][2], al[2][2], bh[2][2], bl[2][2];
        ah[0][0] = *(const bf16x8*)&As[0][arow0][a00];
        ah[0][1] = *(const bf16x8*)&As[0][arow0][a01];
        ah[1][0] = *(const bf16x8*)&As[0][arow1][a10];
        ah[1][1] = *(const bf16x8*)&As[0][arow1][a11];
        al[0][0] = *(const bf16x8*)&As[1][arow0][a00];
        al[0][1] = *(const bf16x8*)&As[1][arow0][a01];
        al[1][0] = *(const bf16x8*)&As[1][arow1][a10];
        al[1][1] = *(const bf16x8*)&As[1][arow1][a11];
        bh[0][0] = *(const bf16x8*)&Bs[0][brow0][b00];
        bh[0][1] = *(const bf16x8*)&Bs[0][brow0][b01];
        bh[1][0] = *(const bf16x8*)&Bs[0][brow1][b10];
        bh[1][1] = *(const bf16x8*)&Bs[0][brow1][b11];
        bl[0][0] = *(const bf16x8*)&Bs[1][brow0][b00];
        bl[0][1] = *(const bf16x8*)&Bs[1][brow0][b01];
        bl[1][0] = *(const bf16x8*)&Bs[1][brow1][b10];
        bl[1][1] = *(const bf16x8*)&Bs[1][brow1][b11];

#pragma unroll
        for (int i = 0; i < 2; ++i)
#pragma unroll
            for (int j = 0; j < 2; ++j)
#pragma unroll
                for (int kk = 0; kk < 2; ++kk){
                    acc[i][j] = __builtin_amdgcn_mfma_f32_32x32x16_bf16(ah[i][kk], bh[j][kk], acc[i][j], 0, 0, 0);
                    acc[i][j] = __builtin_amdgcn_mfma_f32_32x32x16_bf16(ah[i][kk], bl[j][kk], acc[i][j], 0, 0, 0);
                    acc[i][j] = __builtin_amdgcn_mfma_f32_32x32x16_bf16(al[i][kk], bh[j][kk], acc[i][j], 0, 0, 0);
                }
        __syncthreads();
    }

    // C/D layout (32x32, HW-verified): col = lane&31, row = (reg&3) + 8*(reg>>2) + 4*(lane>>5)
#pragma unroll
    for (int i = 0; i < 2; ++i){
#pragma unroll
        for (int j = 0; j < 2; ++j){
            int colc = col0 + wn + j * 32 + l31;
#pragma unroll
            for (int r = 0; r < 16; ++r){
                int row = row0 + wm + i * 32 + (r & 3) + 8 * (r >> 2) + 4 * hi;
                if (row < M) Cbf[(size_t)row * Nn + colc] = f2bf(acc[i][j][r]);
            }
        }
    }
}

// ---------------- per-node attention score dots (bf16 h) ----------------
__global__ __launch_bounds__(256) void k_esd(const u16* __restrict__ h, const float* __restrict__ asrc,
                                             const float* __restrict__ adst,
                                             float* __restrict__ es, float* __restrict__ ed){
    int n = blockIdx.x;
    int tid = threadIdx.x;
    int w = tid >> 6, lane = tid & 63;
    float4 hv = bf4_to_f4(*(const ushort4*)(h + (size_t)n * DHID + w * CPH + lane * 4));
    float4 av = *(const float4*)(asrc + w * CPH + lane * 4);
    float4 dv = *(const float4*)(adst + w * CPH + lane * 4);
    float s = hv.x * av.x + hv.y * av.y + hv.z * av.z + hv.w * av.w;
    float d = hv.x * dv.x + hv.y * dv.y + hv.z * dv.z + hv.w * dv.w;
    for (int off = 32; off > 0; off >>= 1){
        s += __shfl_down(s, off);
        d += __shfl_down(d, off);
    }
    if (lane == 0){ es[n * HEADS + w] = s; ed[n * HEADS + w] = d; }
}

// ---------------- wave-per-node segment softmax + aggregation + bias + elu + split write ----------------
__global__ __launch_bounds__(256) void k_agg(const u16* __restrict__ hsrc, const float* __restrict__ es,
                                             const float* __restrict__ ed, const int* __restrict__ rowptr,
                                             const int* __restrict__ col, const float* __restrict__ bias,
                                             u16* __restrict__ outhi, u16* __restrict__ outlo,
                                             int writeLo, int N){
    int n = blockIdx.x * 4 + (threadIdx.x >> 6);
    if (n >= N) return;
    int lane = threadIdx.x & 63;
    int rp0 = rowptr[n];
    int deg = rowptr[n + 1] - rp0;
    int total = deg + 1;                         // + implicit self-loop
    float4 edv = *(const float4*)(ed + (size_t)n * HEADS);

    // pass 1: per-head max over incoming edges
    float4 mx = make_float4(-FLT_BIG, -FLT_BIG, -FLT_BIG, -FLT_BIG);
    for (int i = lane; i < total; i += 64){
        int s = (i < deg) ? col[rp0 + i] : n;
        float4 ev = *(const float4*)(es + (size_t)s * HEADS);
        mx.x = fmaxf(mx.x, lrelu(ev.x + edv.x));
        mx.y = fmaxf(mx.y, lrelu(ev.y + edv.y));
        mx.z = fmaxf(mx.z, lrelu(ev.z + edv.z));
        mx.w = fmaxf(mx.w, lrelu(ev.w + edv.w));
    }
#pragma unroll
    for (int off = 1; off < 64; off <<= 1){
        mx.x = fmaxf(mx.x, __shfl_xor(mx.x, off));
        mx.y = fmaxf(mx.y, __shfl_xor(mx.y, off));
        mx.z = fmaxf(mx.z, __shfl_xor(mx.z, off));
        mx.w = fmaxf(mx.w, __shfl_xor(mx.w, off));
    }

    // pass 2: per-head sum of exp(e - m)  (es now L1-hot)
    float4 sm = make_float4(0.f, 0.f, 0.f, 0.f);
    for (int i = lane; i < total; i += 64){
        int s = (i < deg) ? col[rp0 + i] : n;
        float4 ev = *(const float4*)(es + (size_t)s * HEADS);
        sm.x += expf(lrelu(ev.x + edv.x) - mx.x);
        sm.y += expf(lrelu(ev.y + edv.y) - mx.y);
        sm.z += expf(lrelu(ev.z + edv.z) - mx.z);
        sm.w += expf(lrelu(ev.w + edv.w) - mx.w);
    }
#pragma unroll
    for (int off = 1; off < 64; off <<= 1){
        sm.x += __shfl_xor(sm.x, off);
        sm.y += __shfl_xor(sm.y, off);
        sm.z += __shfl_xor(sm.z, off);
        sm.w += __shfl_xor(sm.w, off);
    }
    float4 inv = make_float4(1.f / (sm.x + 1e-16f), 1.f / (sm.y + 1e-16f),
                             1.f / (sm.z + 1e-16f), 1.f / (sm.w + 1e-16f));

    // pass 3: weighted aggregation — wave reads the full 2KB row per edge (4 x 512B)
    float4 a0 = make_float4(0.f,0.f,0.f,0.f), a1 = a0, a2 = a0, a3 = a0;
    int c4 = lane * 4;
    for (int i = 0; i < total; ++i){
        int s = (i < deg) ? col[rp0 + i] : n;           // wave-uniform
        float4 ev = *(const float4*)(es + (size_t)s * HEADS);   // L1-hot broadcast
        const u16* rowp = hsrc + (size_t)s * DHID;
        ushort4 r0 = *(const ushort4*)(rowp + 0 * CPH + c4);
        ushort4 r1 = *(const ushort4*)(rowp + 1 * CPH + c4);
        ushort4 r2 = *(const ushort4*)(rowp + 2 * CPH + c4);
        ushort4 r3 = *(const ushort4*)(rowp + 3 * CPH + c4);
        float alx = expf(lrelu(ev.x + edv.x) - mx.x) * inv.x;
        float aly = expf(lrelu(ev.y + edv.y) - mx.y) * inv.y;
        float alz = expf(lrelu(ev.z + edv.z) - mx.z) * inv.z;
        float alw = expf(lrelu(ev.w + edv.w) - mx.w) * inv.w;
        float4 f0 = bf4_to_f4(r0), f1 = bf4_to_f4(r1), f2 = bf4_to_f4(r2), f3 = bf4_to_f4(r3);
        a0.x = fmaf(alx, f0.x, a0.x); a0.y = fmaf(alx, f0.y, a0.y);
        a0.z = fmaf(alx, f0.z, a0.z); a0.w = fmaf(alx, f0.w, a0.w);
        a1.x = fmaf(aly, f1.x, a1.x); a1.y = fmaf(aly, f1.y, a1.y);
        a1.z = fmaf(aly, f1.z, a1.z); a1.w = fmaf(aly, f1.w, a1.w);
        a2.x = fmaf(alz, f2.x, a2.x); a2.y = fmaf(alz, f2.y, a2.y);
        a2.z = fmaf(alz, f2.z, a2.z); a2.w = fmaf(alz, f2.w, a2.w);
        a3.x = fmaf(alw, f3.x, a3.x); a3.y = fmaf(alw, f3.y, a3.y);
        a3.z = fmaf(alw, f3.z, a3.z); a3.w = fmaf(alw, f3.w, a3.w);
    }

    // epilogue: +bias, elu, bf16 hi(/lo) store per head
#pragma unroll
    for (int h = 0; h < 4; ++h){
        float4 a = (h == 0) ? a0 : (h == 1) ? a1 : (h == 2) ? a2 : a3;
        int cidx = h * CPH + c4;
        float4 bv = *(const float4*)(bias + cidx);
        float ox = eluf(a.x + bv.x);
        float oy = eluf(a.y + bv.y);
        float oz = eluf(a.z + bv.z);
        float ow = eluf(a.w + bv.w);
        ushort4 h4;
        h4.x = f2bf(ox); h4.y = f2bf(oy); h4.z = f2bf(oz); h4.w = f2bf(ow);
        *(ushort4*)(outhi + (size_t)n * DHID + cidx) = h4;
        if (writeLo){
            ushort4 l4;
            l4.x = f2bf(ox - bf2f(h4.x));
            l4.y = f2bf(oy - bf2f(h4.y));
            l4.z = f2bf(oz - bf2f(h4.z));
            l4.w = f2bf(ow - bf2f(h4.w));
            *(ushort4*)(outlo + (size_t)n * DHID + cidx) = l4;
        }
    }
}

// ---------------- two-stage per-graph mean/max pooling (bf16 input) ----------------
__global__ __launch_bounds__(256) void k_pool_init(float* __restrict__ gsum, float* __restrict__ gmax, int L){
    int i = blockIdx.x * blockDim.x + threadIdx.x;
    if (i < L){ gsum[i] = 0.f; gmax[i] = -FLT_BIG; }
}

__global__ __launch_bounds__(256) void k_pool_partial(const u16* __restrict__ hf,
                                                      const int* __restrict__ batch,
                                                      float* __restrict__ gsum, float* __restrict__ gmax,
                                                      int N){
    int c = blockIdx.y * 256 + threadIdx.x;
    int i0 = blockIdx.x * PCHUNK;
    int i1 = i0 + PCHUNK; if (i1 > N) i1 = N;
    int curg = batch[i0];
    float s = 0.f, m = -FLT_BIG;
    for (int i = i0; i < i1; ++i){
        int g = batch[i];
        if (g != curg){
            atomicAdd(&gsum[(size_t)curg * DHID + c], s);
            atomicMaxF(&gmax[(size_t)curg * DHID + c], m);
            s = 0.f; m = -FLT_BIG; curg = g;
        }
        float v = bf2f(hf[(size_t)i * DHID + c]);
        s += v;
        m = fmaxf(m, v);
    }
    atomicAdd(&gsum[(size_t)curg * DHID + c], s);
    atomicMaxF(&gmax[(size_t)curg * DHID + c], m);
}

__global__ __launch_bounds__(256) void k_pool_final(const float* __restrict__ gsum,
                                                    const float* __restrict__ gmax,
                                                    const int* __restrict__ lo, const int* __restrict__ hi,
                                                    float* __restrict__ gfeat){
    int g = blockIdx.x;
    int c = threadIdx.x * 4;
    int l = lo[g], h2 = hi[g];
    int cnt = (h2 > l) ? (h2 - l) : 0;
    float invc = 1.f / (float)((cnt > 1) ? cnt : 1);
    float4 s = *(const float4*)(gsum + (size_t)g * DHID + c);
    float4 m = *(const float4*)(gmax + (size_t)g * DHID + c);
    float4 mean = make_float4(s.x * invc, s.y * invc, s.z * invc, s.w * invc);
    if (cnt == 0) m = make_float4(0.f, 0.f, 0.f, 0.f);
    *(float4*)(gfeat + (size_t)g * 2048 + c)        = mean;
    *(float4*)(gfeat + (size_t)g * 2048 + 1024 + c) = m;
}

// ---------------- small FC ----------------
__global__ __launch_bounds__(256) void k_fc(const float* __restrict__ X, const float* __restrict__ W,
                                            const float* __restrict__ b, float* __restrict__ Y,
                                            int K, int Nc, int relu){
    __shared__ float xr[2048];
    int r = blockIdx.y;
    int tid = threadIdx.x;
    for (int i = tid; i < K; i += 256) xr[i] = X[(size_t)r * K + i];
    __syncthreads();
    int c = blockIdx.x * 256 + tid;
    if (c >= Nc) return;
    float acc = b[c];
    for (int k = 0; k < K; ++k) acc += xr[k] * W[(size_t)k * Nc + c];
    if (relu) acc = fmaxf(acc, 0.f);
    Y[(size_t)r * Nc + c] = acc;
}

// ---------------- launch ----------------
extern "C" void kernel_launch(void* const* d_in, const int* in_sizes, int n_in,
                              void* d_out, int out_size, void* d_ws, size_t ws_size,
                              hipStream_t stream) {
    const float* x      = (const float*)d_in[0];
    const int*   ei     = (const int*)  d_in[1];
    const int*   batch  = (const int*)  d_in[2];
    const float* W1     = (const float*)d_in[3];
    const float* asrc1  = (const float*)d_in[4];
    const float* adst1  = (const float*)d_in[5];
    const float* b1     = (const float*)d_in[6];
    const float* W2     = (const float*)d_in[7];
    const float* asrc2  = (const float*)d_in[8];
    const float* adst2  = (const float*)d_in[9];
    const float* b2     = (const float*)d_in[10];
    const float* Wc1    = (const float*)d_in[11];
    const float* bc1    = (const float*)d_in[12];
    const float* Wc2    = (const float*)d_in[13];
    const float* bc2    = (const float*)d_in[14];
    const float* Wc3    = (const float*)d_in[15];
    const float* bc3    = (const float*)d_in[16];

    const int N = in_sizes[2];
    const int E = in_sizes[1] / 2;
    const int G = out_size / 5;
    const int DIN = in_sizes[0] / N;

    const int* srcI = ei;
    const int* dstI = ei + E;

    char* p = (char*)d_ws;
    auto alloc = [&](size_t bytes) -> void* {
        void* q = (void*)p;
        p += (bytes + 255) & ~(size_t)255;
        return q;
    };
    u16*   R1     = (u16*)alloc((size_t)N * DHID * 2 * 2);   // activations hi+lo
    u16*   R2     = (u16*)alloc((size_t)N * DHID * 2);       // bf16 h plane
    float* es     = (float*)alloc((size_t)N * HEADS * 4);
    float* ed     = (float*)alloc((size_t)N * HEADS * 4);
    float* gfeat  = (float*)alloc((size_t)G * 2048 * 4);
    float* gsum   = (float*)alloc((size_t)G * DHID * 4);
    float* gmax   = (float*)alloc((size_t)G * DHID * 4);
    float* z1     = (float*)alloc((size_t)G * 512 * 4);
    float* z2     = (float*)alloc((size_t)G * 256 * 4);
    int*   cnt    = (int*)  alloc((size_t)N * 4);
    int*   fill   = (int*)  alloc((size_t)N * 4);
    int*   rowptr = (int*)  alloc((size_t)(N + 1) * 4);
    int*   col    = (int*)  alloc((size_t)E * 4);
    int*   lo     = (int*)  alloc((size_t)G * 4);
    int*   hi     = (int*)  alloc((size_t)G * 4);
    u16*   w1th   = (u16*)  alloc((size_t)DIN * DHID * 2);
    u16*   w1tl   = (u16*)  alloc((size_t)DIN * DHID * 2);
    u16*   w2th   = (u16*)  alloc((size_t)DHID * DHID * 2);
    u16*   w2tl   = (u16*)  alloc((size_t)DHID * DHID * 2);
    float* logits = (float*)d_out;

    int nb = (N + 255) / 256;
    int ebp = (E + 255) / 256;
    int aggb = (N + 3) / 4;

    // CSR + pooling bounds
    k_init   <<<nb,  256, 0, stream>>>(cnt, fill, lo, hi, N, G);
    k_count  <<<ebp, 256, 0, stream>>>(dstI, cnt, E);
    k_scan   <<<1,  1024, 0, stream>>>(cnt, rowptr, N, E);
    k_scatter<<<ebp, 256, 0, stream>>>(srcI, dstI, rowptr, fill, col, E);
    k_bounds <<<nb,  256, 0, stream>>>(batch, lo, hi, N);

    // weight splits (with LDS-tiled transpose)
    k_splitT<<<dim3((DHID + 31) / 32, (DIN + 31) / 32),  256, 0, stream>>>(W1, w1th, w1tl, DIN, DHID);
    k_splitT<<<dim3((DHID + 31) / 32, (DHID + 31) / 32), 256, 0, stream>>>(W2, w2th, w2tl, DHID, DHID);

    int R = (N + 127) / 128;
    int Rchunk = (R + 7) / 8;
    dim3 gemmGrd(8, 8 * Rchunk);   // XCD swizzle: x = row-chunk, y = (local row, col-block)

    // ---- GAT layer 1 ----
    u16* a1h = R1;
    u16* a1l = R1 + (size_t)N * DIN;
    long L41 = (long)N * DIN / 4;
    k_split<<<(unsigned)((L41 + 255) / 256), 256, 0, stream>>>(x, a1h, a1l, L41);
    u16* h1 = R2;
    k_gemm_mfma<<<gemmGrd, 256, 0, stream>>>(a1h, a1l, w1th, w1tl, h1, N, DIN, DHID, Rchunk);
    k_esd<<<N, 256, 0, stream>>>(h1, asrc1, adst1, es, ed);
    u16* o1h = R1;
    u16* o1l = R1 + (size_t)N * DHID;
    k_agg<<<aggb, 256, 0, stream>>>(h1, es, ed, rowptr, col, b1, o1h, o1l, 1, N);

    // ---- GAT layer 2 ----
    u16* h2 = R2;
    k_gemm_mfma<<<gemmGrd, 256, 0, stream>>>(o1h, o1l, w2th, w2tl, h2, N, DHID, DHID, Rchunk);
    k_esd<<<N, 256, 0, stream>>>(h2, asrc2, adst2, es, ed);
    u16* o2h = R1;
    k_agg<<<aggb, 256, 0, stream>>>(h2, es, ed, rowptr, col, b2, o2h, (u16*)0, 0, N);

    // ---- pooling + classifier ----
    k_pool_init<<<(G * DHID + 255) / 256, 256, 0, stream>>>(gsum, gmax, G * DHID);
    dim3 poolGrd((N + PCHUNK - 1) / PCHUNK, DHID / 256);
    k_pool_partial<<<poolGrd, 256, 0, stream>>>(o2h, batch, gsum, gmax, N);
    k_pool_final<<<G, 256, 0, stream>>>(gsum, gmax, lo, hi, gfeat);

    k_fc<<<dim3(2, G), 256, 0, stream>>>(gfeat, Wc1, bc1, z1, 2048, 512, 1);
    k_fc<<<dim3(1, G), 256, 0, stream>>>(z1,    Wc2, bc2, z2, 512,  256, 1);
    k_fc<<<dim3(1, G), 256, 0, stream>>>(z2,    Wc3, bc3, logits, 256, 5, 0);
}